// Round 5
// baseline (1487.195 us; speedup 1.0000x reference)
//
#include <hip/hip_runtime.h>

typedef __bf16 bf16;
typedef __bf16 bf16x8 __attribute__((ext_vector_type(8)));
typedef float f32x4 __attribute__((ext_vector_type(4)));

#define NB 8
#define NC 1024
#define NCI 512
#define ND 256
#define NP 6272   // 8*28*28
#define NM 1568   // 8*14*14

// ---------------- weight cast ----------------
__global__ void cast_f32_bf16(const float* __restrict__ in, bf16* __restrict__ out, int n) {
    int i = blockIdx.x * blockDim.x + threadIdx.x;
    int stride = gridDim.x * blockDim.x;
    for (; i < n; i += stride) out[i] = (bf16)in[i];
}

// ---------------- BN constants ----------------
__global__ void bn_pre(const float* __restrict__ g, const float* __restrict__ be,
                       const float* __restrict__ rm, const float* __restrict__ rv,
                       const float* __restrict__ bw, float* __restrict__ alpha,
                       float* __restrict__ betaE) {
    int i = blockIdx.x * 256 + threadIdx.x;
    if (i < NC) {
        float inv = g[i] * rsqrtf(rv[i] + 1e-5f);
        alpha[i] = inv;
        betaE[i] = be[i] - rm[i] * inv + bw[i] * inv;
    }
}

// ---------------- maxpool(1,2,2) + transpose -> xpT (b, m, c) bf16 ----------------
__global__ __launch_bounds__(256)
void pool_transpose(const float* __restrict__ x, bf16* __restrict__ xpT) {
    __shared__ float tile[32][33];
    int b = blockIdx.z;
    int m0 = blockIdx.x * 32, c0 = blockIdx.y * 32;
    int tx = threadIdx.x & 31, ty = threadIdx.x >> 5;
    int m = m0 + tx;
    int tq = m / 196, rem = m % 196;
    int iq = rem / 14, jq = rem % 14;
    long sb = ((long)(b * NC + c0) * NP) + tq * 784 + iq * 56 + jq * 2;
#pragma unroll
    for (int u = 0; u < 4; ++u) {
        int c = ty + 8 * u;
        const float* s = x + sb + (long)c * NP;
        tile[c][tx] = fmaxf(fmaxf(s[0], s[1]), fmaxf(s[28], s[29]));
    }
    __syncthreads();
#pragma unroll
    for (int u = 0; u < 4; ++u) {
        int mm = ty + 8 * u;
        xpT[((long)b * NM + m0 + mm) * NC + c0 + tx] = (bf16)tile[tx][mm];
    }
}

// ---------------- transpose one batch of x -> xT (p, c) bf16 ----------------
__global__ __launch_bounds__(256)
void transpose_x(const float* __restrict__ x, bf16* __restrict__ xT, int b) {
    __shared__ float tile[32][33];
    int p0 = blockIdx.x * 32, c0 = blockIdx.y * 32;
    int tx = threadIdx.x & 31, ty = threadIdx.x >> 5;
#pragma unroll
    for (int u = 0; u < 4; ++u) {
        int c = ty + 8 * u;
        tile[c][tx] = x[((long)(b * NC + c0 + c)) * NP + p0 + tx];
    }
    __syncthreads();
#pragma unroll
    for (int u = 0; u < 4; ++u) {
        int pp = ty + 8 * u;
        xT[((long)(p0 + pp)) * NC + c0 + tx] = (bf16)tile[tx][pp];
    }
}

// ---------------- generic bf16 GEMM: Out[r][c] = sum_k A[r][k]*Bt[c][k] (+epilogue) ----
// epi: 0 = +bias[col] -> bf16 out; 1 = +bias[row] -> bf16 out;
//      2 = acc*alpha[row] + betaE[row] + xres -> f32 out
__global__ __launch_bounds__(256)
void gemm_bt(const bf16* __restrict__ A, long a_bs, int lda,
             const bf16* __restrict__ Bt, long b_bs, int ldb,
             void* __restrict__ Out, long o_bs, int ldo,
             int Mdim, int Ndim, int Kdim, int epi,
             const float* __restrict__ e0, const float* __restrict__ e1,
             const float* __restrict__ xres, long x_bs)
{
    __shared__ bf16 As[128][72];
    __shared__ bf16 Bs[128][72];
    const int t = threadIdx.x;
    const int l = t & 63;
    const int w = t >> 6;
    const int wr = w >> 1, wc = w & 1;
    const int bz = blockIdx.z;
    const int row0 = blockIdx.y * 128;
    const int col0 = blockIdx.x * 128;
    A += a_bs * bz;
    Bt += b_bs * bz;

    const int sr = t >> 3;         // 0..31
    const int sk = (t & 7) * 8;    // 0..56

    f32x4 acc[4][4] = {};
    for (int kt = 0; kt < Kdim; kt += 64) {
#pragma unroll
        for (int u = 0; u < 4; ++u) {
            int r = sr + 32 * u;
            *(bf16x8*)&As[r][sk] = *(const bf16x8*)(A + (long)(row0 + r) * lda + kt + sk);
            *(bf16x8*)&Bs[r][sk] = *(const bf16x8*)(Bt + (long)(col0 + r) * ldb + kt + sk);
        }
        __syncthreads();
#pragma unroll
        for (int ks = 0; ks < 2; ++ks) {
            const int kk = 8 * (l >> 4) + 32 * ks;
            bf16x8 af[4], bfr[4];
#pragma unroll
            for (int mi = 0; mi < 4; ++mi)
                af[mi] = *(const bf16x8*)&As[64 * wr + 16 * mi + (l & 15)][kk];
#pragma unroll
            for (int ni = 0; ni < 4; ++ni)
                bfr[ni] = *(const bf16x8*)&Bs[64 * wc + 16 * ni + (l & 15)][kk];
#pragma unroll
            for (int mi = 0; mi < 4; ++mi)
#pragma unroll
                for (int ni = 0; ni < 4; ++ni)
                    acc[mi][ni] = __builtin_amdgcn_mfma_f32_16x16x32_bf16(
                        af[mi], bfr[ni], acc[mi][ni], 0, 0, 0);
        }
        __syncthreads();
    }
#pragma unroll
    for (int mi = 0; mi < 4; ++mi) {
        int rbase = row0 + 64 * wr + 16 * mi + 4 * (l >> 4);
#pragma unroll
        for (int ni = 0; ni < 4; ++ni) {
            int col = col0 + 64 * wc + 16 * ni + (l & 15);
            if (col >= Ndim) continue;
            f32x4 v = acc[mi][ni];
#pragma unroll
            for (int i = 0; i < 4; ++i) {
                int r = rbase + i;
                if (r >= Mdim) continue;
                if (epi == 2) {
                    float* o = (float*)Out + o_bs * bz;
                    o[(long)r * ldo + col] =
                        v[i] * e0[r] + e1[r] + xres[x_bs * bz + (long)r * ldo + col];
                } else {
                    bf16* o = (bf16*)Out + o_bs * bz;
                    float bias = (epi == 0) ? e0[col] : e0[r];
                    o[(long)r * ldo + col] = (bf16)(v[i] + bias);
                }
            }
        }
    }
}

// ---------------- fused attention: y = softmax(th@ph /16) @ g ----------------
// thT (b, p, ci): Q rows, d contiguous.  phT (b, m, ci): K rows, d contiguous.
// g (b, ci, m): m contiguous.  yT out (b, p, ci).
__global__ __launch_bounds__(256)
void attn(const bf16* __restrict__ thT, const bf16* __restrict__ phT,
          const bf16* __restrict__ g, bf16* __restrict__ yT)
{
    __shared__ bf16 phs[32][264];      // [m][d]
    __shared__ bf16 gs[256][40];       // [d][m]
    __shared__ bf16 ps[4][16][40];     // per-wave P tile [n][m]
    const int t = threadIdx.x;
    const int l = t & 63, w = t >> 6;
    const int bh = blockIdx.y;
    const int b = bh >> 1, head = bh & 1;
    const int n0 = blockIdx.x * 64 + w * 16;
    const bf16* thb = thT + (long)b * NP * NCI + head * ND;
    const bf16* phb = phT + (long)b * NM * NCI + head * ND;
    const bf16* gb = g + ((long)b * NCI + head * ND) * NM;

    bf16x8 q[8];
    {
        int qr = n0 + (l & 15);
#pragma unroll
        for (int ks = 0; ks < 8; ++ks)
            q[ks] = *(const bf16x8*)(thb + (long)qr * NCI + ks * 32 + 8 * (l >> 4));
    }
    f32x4 yacc[16] = {};
    float mrun[4], lrun[4];
#pragma unroll
    for (int i = 0; i < 4; ++i) { mrun[i] = -1e30f; lrun[i] = 0.f; }

    const int smm = t >> 3;          // phs row 0..31
    const int sdb = (t & 7) * 32;    // d base

    for (int ch = 0; ch < 49; ++ch) {
        int m0 = ch * 32;
#pragma unroll
        for (int u = 0; u < 4; ++u)
            *(bf16x8*)&phs[smm][sdb + 8 * u] =
                *(const bf16x8*)(phb + (long)(m0 + smm) * NCI + sdb + 8 * u);
#pragma unroll
        for (int u = 0; u < 4; ++u)
            *(bf16x8*)&gs[t][8 * u] = *(const bf16x8*)(gb + (long)t * NM + m0 + 8 * u);
        __syncthreads();

        f32x4 s0 = {}, s1 = {};
#pragma unroll
        for (int ks = 0; ks < 8; ++ks) {
            const int kk = 8 * (l >> 4) + 32 * ks;
            bf16x8 b0 = *(const bf16x8*)&phs[(l & 15)][kk];
            bf16x8 b1 = *(const bf16x8*)&phs[(l & 15) + 16][kk];
            s0 = __builtin_amdgcn_mfma_f32_16x16x32_bf16(q[ks], b0, s0, 0, 0, 0);
            s1 = __builtin_amdgcn_mfma_f32_16x16x32_bf16(q[ks], b1, s1, 0, 0, 0);
        }
        float corr[4];
#pragma unroll
        for (int i = 0; i < 4; ++i) {
            float a0 = s0[i] * 0.0625f, a1 = s1[i] * 0.0625f;
            float cm = fmaxf(a0, a1);
            cm = fmaxf(cm, __shfl_xor(cm, 1));
            cm = fmaxf(cm, __shfl_xor(cm, 2));
            cm = fmaxf(cm, __shfl_xor(cm, 4));
            cm = fmaxf(cm, __shfl_xor(cm, 8));
            float mn = fmaxf(mrun[i], cm);
            corr[i] = __expf(mrun[i] - mn);
            float p0 = __expf(a0 - mn);
            float p1 = __expf(a1 - mn);
            float rs = p0 + p1;
            rs += __shfl_xor(rs, 1);
            rs += __shfl_xor(rs, 2);
            rs += __shfl_xor(rs, 4);
            rs += __shfl_xor(rs, 8);
            lrun[i] = lrun[i] * corr[i] + rs;
            mrun[i] = mn;
            int prow = 4 * (l >> 4) + i;
            ps[w][prow][(l & 15)] = (bf16)p0;
            ps[w][prow][(l & 15) + 16] = (bf16)p1;
        }
#pragma unroll
        for (int ti = 0; ti < 16; ++ti)
#pragma unroll
            for (int i = 0; i < 4; ++i) yacc[ti][i] *= corr[i];

        bf16x8 pa = *(const bf16x8*)&ps[w][(l & 15)][8 * (l >> 4)];
#pragma unroll
        for (int ti = 0; ti < 16; ++ti) {
            bf16x8 gv = *(const bf16x8*)&gs[(l & 15) + 16 * ti][8 * (l >> 4)];
            yacc[ti] = __builtin_amdgcn_mfma_f32_16x16x32_bf16(pa, gv, yacc[ti], 0, 0, 0);
        }
        __syncthreads();
    }
    bf16* yb = yT + (long)b * NP * NCI + head * ND;
    float invl[4];
#pragma unroll
    for (int i = 0; i < 4; ++i) invl[i] = 1.0f / lrun[i];
#pragma unroll
    for (int ti = 0; ti < 16; ++ti)
#pragma unroll
        for (int i = 0; i < 4; ++i) {
            int row = n0 + 4 * (l >> 4) + i;
            int col = (l & 15) + 16 * ti;
            yb[(long)row * NCI + col] = (bf16)(yacc[ti][i] * invl[i]);
        }
}

extern "C" void kernel_launch(void* const* d_in, const int* in_sizes, int n_in,
                              void* d_out, int out_size, void* d_ws, size_t ws_size,
                              hipStream_t stream)
{
    const float* x     = (const float*)d_in[0];
    const float* Wg    = (const float*)d_in[1];
    const float* bg    = (const float*)d_in[2];
    const float* Wth   = (const float*)d_in[3];
    const float* bth   = (const float*)d_in[4];
    const float* Wph   = (const float*)d_in[5];
    const float* bph   = (const float*)d_in[6];
    const float* Wwm   = (const float*)d_in[7];
    const float* bw    = (const float*)d_in[8];
    const float* gamma = (const float*)d_in[9];
    const float* beta  = (const float*)d_in[10];
    const float* rmean = (const float*)d_in[11];
    const float* rvar  = (const float*)d_in[12];
    float* out = (float*)d_out;
    (void)in_sizes; (void)n_in; (void)out_size; (void)ws_size;

    char* ws = (char*)d_ws;
    size_t off = 0;
    auto take = [&](size_t n) { char* p = ws + off; off += (n + 255) & ~(size_t)255; return p; };

    float* alpha = (float*)take(NC * 4);
    float* betaE = (float*)take(NC * 4);
    bf16* WgB  = (bf16*)take((size_t)NCI * NC * 2);
    bf16* WthB = (bf16*)take((size_t)NCI * NC * 2);
    bf16* WphB = (bf16*)take((size_t)NCI * NC * 2);
    bf16* WwB  = (bf16*)take((size_t)NC * NCI * 2);
    bf16* xpT  = (bf16*)take((size_t)NB * NM * NC * 2);   // (b, m, c)
    bf16* gbuf = (bf16*)take((size_t)NB * NCI * NM * 2);  // (b, o, m)  [also OOB slack for xpT]
    bf16* phT  = (bf16*)take((size_t)NB * NM * NCI * 2);  // (b, m, o)
    bf16* thT  = (bf16*)take((size_t)NB * NP * NCI * 2);  // (b, p, o)
    bf16* yT   = (bf16*)take((size_t)NB * NP * NCI * 2);  // (b, p, o)
    bf16* xT1  = (bf16*)take((size_t)NP * NC * 2);        // one batch (p, c)

    cast_f32_bf16<<<512, 256, 0, stream>>>(Wg, WgB, NCI * NC);
    cast_f32_bf16<<<512, 256, 0, stream>>>(Wth, WthB, NCI * NC);
    cast_f32_bf16<<<512, 256, 0, stream>>>(Wph, WphB, NCI * NC);
    cast_f32_bf16<<<512, 256, 0, stream>>>(Wwm, WwB, NC * NCI);
    bn_pre<<<4, 256, 0, stream>>>(gamma, beta, rmean, rvar, bw, alpha, betaE);

    pool_transpose<<<dim3(49, 32, 8), 256, 0, stream>>>(x, xpT);

    for (int b = 0; b < NB; ++b) {
        transpose_x<<<dim3(196, 32), 256, 0, stream>>>(x, xT1, b);
        // thT[b][p][o] = sum_c xT1[p][c] * Wth[o][c] + bth[o]
        gemm_bt<<<dim3(4, 49, 1), 256, 0, stream>>>(
            xT1, 0, NC, WthB, 0, NC,
            thT + (size_t)b * NP * NCI, 0, NCI,
            NP, NCI, NC, 0, bth, nullptr, nullptr, 0);
    }
    // phT[b][m][o] = sum_c xpT[b][m][c] * Wph[o][c] + bph[o]
    gemm_bt<<<dim3(4, 13, 8), 256, 0, stream>>>(
        xpT, (long)NM * NC, NC, WphB, 0, NC,
        phT, (long)NM * NCI, NCI,
        NM, NCI, NC, 0, bph, nullptr, nullptr, 0);
    // g[b][o][m] = sum_c Wg[o][c] * xpT[b][m][c] + bg[o]
    gemm_bt<<<dim3(13, 4, 8), 256, 0, stream>>>(
        WgB, 0, NC, xpT, (long)NM * NC, NC,
        gbuf, (long)NCI * NM, NM,
        NCI, NM, NC, 1, bg, nullptr, nullptr, 0);

    attn<<<dim3(98, 16), 256, 0, stream>>>(thT, phT, gbuf, yT);

    // out[b][co][p] = (sum_o Ww[co][o]*yT[b][p][o]) * alpha[co] + betaE[co] + x[b][co][p]
    gemm_bt<<<dim3(49, 8, 8), 256, 0, stream>>>(
        WwB, 0, NCI, yT, (long)NP * NCI, NCI,
        out, (long)NC * NP, NP,
        NC, NP, NCI, 2, alpha, betaE, x, (long)NC * NP);
}